// Round 5
// baseline (58.413 us; speedup 1.0000x reference)
//
#include <hip/hip_runtime.h>
#include <math.h>

#define NQ   10
#define DIMQ 1024
#define BATCH_ROWS 16384

typedef unsigned uv2 __attribute__((ext_vector_type(2)));
typedef float f32x4 __attribute__((ext_vector_type(4)));

#if __has_builtin(__builtin_amdgcn_permlane32_swap)
#define HAS_PLS32 1
#else
#define HAS_PLS32 0
#endif
#if __has_builtin(__builtin_amdgcn_permlane16_swap)
#define HAS_PLS16 1
#else
#define HAS_PLS16 0
#endif

// butterfly on a local register pair: a' = a + i*b ; b' = b + i*a
#define BFLY(ar, ai, br, bi) do {            \
    float _tr = (ar), _ti = (ai);            \
    (ar) = (ar) - (bi); (ai) = (ai) + (br);  \
    (br) = (br) - _ti;  (bi) = (bi) + _tr;   \
} while (0)

// ---------------------------------------------------------------------------
// Diagonal precompute (3 x 1024 float2) into ws.
// ---------------------------------------------------------------------------
__global__ void qdiag_precompute(const float* __restrict__ alphas,
                                 const float* __restrict__ betas,
                                 const float* __restrict__ thetas,
                                 const float* __restrict__ phis,
                                 float2* __restrict__ ws) {
    const int e = threadIdx.x;
    float pin = 0.f, pt = 0.f, pp = 0.f;
#pragma unroll
    for (int p = 0; p < NQ; ++p) {
        const int q = NQ - 1 - p;
        if ((e >> p) & 1) {
            pin += betas[q];
        } else {
            pin += alphas[q];
            pt  += thetas[q];
            pp  += phis[q];
        }
    }
    float s, c;
    sincosf(pin, &s, &c);
    ws[e] = make_float2(c, s);
    sincosf(pt, &s, &c);
    ws[DIMQ + e] = make_float2(c * 0.03125f, s * 0.03125f);
    sincosf(pp, &s, &c);
    ws[2 * DIMQ + e] = make_float2(c * 0.03125f, s * 0.03125f);
}

// ---------------------------------------------------------------------------
// Cross-lane primitives
// ---------------------------------------------------------------------------
template <int CTRL>
__device__ __forceinline__ float dpp_mov(float x) {
    return __int_as_float(
        __builtin_amdgcn_update_dpp(0, __float_as_int(x), CTRL, 0xF, 0xF, true));
}

template <int PAT>
__device__ __forceinline__ float ds_swz(float x) {
    return __int_as_float(__builtin_amdgcn_ds_swizzle(__float_as_int(x), PAT));
}

// DPP ctrl encodings
#define DPP_XOR1   0xB1   // quad_perm [1,0,3,2]
#define DPP_XOR2   0x4E   // quad_perm [2,3,0,1]
// ds_swizzle bitmode: offset = xor<<10 | 0x1F
#define SWZ_XOR4  0x101F
#define SWZ_XOR8  0x201F
#define SWZ_XOR16 0x401F

// permlane{16,32}_swap based butterfly on TWO complex values at once.
#if HAS_PLS32
__device__ __forceinline__ void pls32_bfly(float& fr, float& fi, float& gr, float& gi) {
    uv2 pr = __builtin_amdgcn_permlane32_swap(__float_as_uint(fr), __float_as_uint(gr), false, false);
    uv2 pi = __builtin_amdgcn_permlane32_swap(__float_as_uint(fi), __float_as_uint(gi), false, false);
    float Ar = __uint_as_float(pr.x) - __uint_as_float(pi.y);
    float Ai = __uint_as_float(pi.x) + __uint_as_float(pr.y);
    float Br = __uint_as_float(pr.y) - __uint_as_float(pi.x);
    float Bi = __uint_as_float(pi.y) + __uint_as_float(pr.x);
    uv2 rr = __builtin_amdgcn_permlane32_swap(__float_as_uint(Ar), __float_as_uint(Br), false, false);
    uv2 ri = __builtin_amdgcn_permlane32_swap(__float_as_uint(Ai), __float_as_uint(Bi), false, false);
    fr = __uint_as_float(rr.x); gr = __uint_as_float(rr.y);
    fi = __uint_as_float(ri.x); gi = __uint_as_float(ri.y);
}
#endif
#if HAS_PLS16
__device__ __forceinline__ void pls16_bfly(float& fr, float& fi, float& gr, float& gi) {
    uv2 pr = __builtin_amdgcn_permlane16_swap(__float_as_uint(fr), __float_as_uint(gr), false, false);
    uv2 pi = __builtin_amdgcn_permlane16_swap(__float_as_uint(fi), __float_as_uint(gi), false, false);
    float Ar = __uint_as_float(pr.x) - __uint_as_float(pi.y);
    float Ai = __uint_as_float(pi.x) + __uint_as_float(pr.y);
    float Br = __uint_as_float(pr.y) - __uint_as_float(pi.x);
    float Bi = __uint_as_float(pi.y) + __uint_as_float(pr.x);
    uv2 rr = __builtin_amdgcn_permlane16_swap(__float_as_uint(Ar), __float_as_uint(Br), false, false);
    uv2 ri = __builtin_amdgcn_permlane16_swap(__float_as_uint(Ai), __float_as_uint(Bi), false, false);
    fr = __uint_as_float(rr.x); gr = __uint_as_float(rr.y);
    fi = __uint_as_float(ri.x); gi = __uint_as_float(ri.y);
}
#endif

// ---------------------------------------------------------------------------
// Runtime self-checks (wave-uniform) for permlane primitives.
// ---------------------------------------------------------------------------
__device__ __forceinline__ bool detect_pls32(unsigned lane) {
#if HAS_PLS32
    uv2 r = __builtin_amdgcn_permlane32_swap(lane, 1000u + lane, false, false);
    const bool lo = lane < 32;
    unsigned ax = lo ? lane : (1000u + lane - 32u);
    unsigned ay = lo ? (lane + 32u) : (1000u + lane);
    unsigned bx = lo ? (1000u + lane + 32u) : lane;
    unsigned by = lo ? (1000u + lane) : (lane - 32u);
    bool ok = (r.x == ax && r.y == ay) || (r.x == bx && r.y == by);
    return __all(ok);
#else
    return false;
#endif
}

__device__ __forceinline__ bool detect_pls16(unsigned lane) {
#if HAS_PLS16
    uv2 r = __builtin_amdgcn_permlane16_swap(lane, 1000u + lane, false, false);
    const bool odd = (lane & 16u) != 0u;
    unsigned ax = odd ? (1000u + lane - 16u) : lane;
    unsigned ay = odd ? (1000u + lane) : (lane + 16u);
    unsigned bx = odd ? lane : (1000u + lane + 16u);
    unsigned by = odd ? (lane - 16u) : (1000u + lane);
    bool ok = (r.x == ax && r.y == ay) || (r.x == bx && r.y == by);
    return __all(ok);
#else
    return false;
#endif
}

// ---------------------------------------------------------------------------
// Diagonal application on the 16-complex register tile. e = j*256 + lane*4 + l
// ---------------------------------------------------------------------------
__device__ __forceinline__ void diag_apply_ws(float re[4][4], float im[4][4],
                                              int lane, const float2* __restrict__ dg) {
#pragma unroll
    for (int j = 0; j < 4; ++j) {
        const float4* dp = (const float4*)(dg + j * 256 + lane * 4);
        const float4 d01 = dp[0];
        const float4 d23 = dp[1];
        float dc[4] = {d01.x, d01.z, d23.x, d23.z};
        float ds[4] = {d01.y, d01.w, d23.y, d23.w};
#pragma unroll
        for (int l = 0; l < 4; ++l) {
            const float r = re[j][l], i = im[j][l];
            re[j][l] = r * dc[l] - i * ds[l];
            im[j][l] = r * ds[l] + i * dc[l];
        }
    }
}

__device__ __forceinline__ void diag_apply_inline(float re[4][4], float im[4][4], int lane,
                                                  const float* __restrict__ p0,
                                                  const float* __restrict__ p1,
                                                  float scale) {
#pragma unroll
    for (int j = 0; j < 4; ++j)
#pragma unroll
        for (int l = 0; l < 4; ++l) {
            const int e = j * 256 + lane * 4 + l;
            float ph = 0.f;
#pragma unroll
            for (int p = 0; p < NQ; ++p) {
                const int q = NQ - 1 - p;
                ph += ((e >> p) & 1) ? (p1 ? p1[q] : 0.f) : p0[q];
            }
            float s, c;
            sincosf(ph, &s, &c);
            c *= scale; s *= scale;
            const float r = re[j][l], i = im[j][l];
            re[j][l] = r * c - i * s;
            im[j][l] = r * s + i * c;
        }
}

// ---------------------------------------------------------------------------
// Beamsplitter transform — pipe-balanced (R2-proven mix):
//  bit0,bit1: register (l); mask1,mask2: DPP quad_perm (VALU);
//  mask4,mask8: ds_swizzle (DS pipe — overlaps other waves' VALU);
//  mask16: permlane16_swap; mask32: permlane32_swap; bit8,bit9: register (j)
// ---------------------------------------------------------------------------
__device__ __forceinline__ void bs_transform(float re[4][4], float im[4][4],
                                             bool p16ok, bool p32ok) {
    // bit 0 (l ^ 1) and bit 1 (l ^ 2): register-local
#pragma unroll
    for (int j = 0; j < 4; ++j) {
        BFLY(re[j][0], im[j][0], re[j][1], im[j][1]);
        BFLY(re[j][2], im[j][2], re[j][3], im[j][3]);
    }
#pragma unroll
    for (int j = 0; j < 4; ++j) {
        BFLY(re[j][0], im[j][0], re[j][2], im[j][2]);
        BFLY(re[j][1], im[j][1], re[j][3], im[j][3]);
    }
    // lane mask 1: DPP quad_perm
#pragma unroll
    for (int j = 0; j < 4; ++j)
#pragma unroll
        for (int l = 0; l < 4; ++l) {
            const float pr = dpp_mov<DPP_XOR1>(re[j][l]);
            const float pi = dpp_mov<DPP_XOR1>(im[j][l]);
            re[j][l] -= pi; im[j][l] += pr;
        }
    // lane mask 2: DPP quad_perm
#pragma unroll
    for (int j = 0; j < 4; ++j)
#pragma unroll
        for (int l = 0; l < 4; ++l) {
            const float pr = dpp_mov<DPP_XOR2>(re[j][l]);
            const float pi = dpp_mov<DPP_XOR2>(im[j][l]);
            re[j][l] -= pi; im[j][l] += pr;
        }
    // lane mask 4: ds_swizzle (DS pipe)
#pragma unroll
    for (int j = 0; j < 4; ++j)
#pragma unroll
        for (int l = 0; l < 4; ++l) {
            const float pr = ds_swz<SWZ_XOR4>(re[j][l]);
            const float pi = ds_swz<SWZ_XOR4>(im[j][l]);
            re[j][l] -= pi; im[j][l] += pr;
        }
    // lane mask 8: ds_swizzle (DS pipe)
#pragma unroll
    for (int j = 0; j < 4; ++j)
#pragma unroll
        for (int l = 0; l < 4; ++l) {
            const float pr = ds_swz<SWZ_XOR8>(re[j][l]);
            const float pi = ds_swz<SWZ_XOR8>(im[j][l]);
            re[j][l] -= pi; im[j][l] += pr;
        }
    // lane mask 16: permlane16_swap (VALU) or swizzle fallback
#if HAS_PLS16
    if (p16ok) {
#pragma unroll
        for (int j = 0; j < 4; ++j) {
            pls16_bfly(re[j][0], im[j][0], re[j][1], im[j][1]);
            pls16_bfly(re[j][2], im[j][2], re[j][3], im[j][3]);
        }
    } else
#endif
    {
#pragma unroll
        for (int j = 0; j < 4; ++j)
#pragma unroll
            for (int l = 0; l < 4; ++l) {
                const float pr = ds_swz<SWZ_XOR16>(re[j][l]);
                const float pi = ds_swz<SWZ_XOR16>(im[j][l]);
                re[j][l] -= pi; im[j][l] += pr;
            }
    }
    // lane mask 32: permlane32_swap (VALU) or shfl fallback
#if HAS_PLS32
    if (p32ok) {
#pragma unroll
        for (int j = 0; j < 4; ++j) {
            pls32_bfly(re[j][0], im[j][0], re[j][1], im[j][1]);
            pls32_bfly(re[j][2], im[j][2], re[j][3], im[j][3]);
        }
    } else
#endif
    {
#pragma unroll
        for (int j = 0; j < 4; ++j)
#pragma unroll
            for (int l = 0; l < 4; ++l) {
                const float pr = __shfl_xor(re[j][l], 32, 64);
                const float pi = __shfl_xor(im[j][l], 32, 64);
                re[j][l] -= pi; im[j][l] += pr;
            }
    }
    // bit 8 (j ^ 1) and bit 9 (j ^ 2): register-local
#pragma unroll
    for (int l = 0; l < 4; ++l) {
        BFLY(re[0][l], im[0][l], re[1][l], im[1][l]);
        BFLY(re[2][l], im[2][l], re[3][l], im[3][l]);
    }
#pragma unroll
    for (int l = 0; l < 4; ++l) {
        BFLY(re[0][l], im[0][l], re[2][l], im[2][l]);
        BFLY(re[1][l], im[1][l], re[3][l], im[3][l]);
    }
}

// ---------------------------------------------------------------------------
// Per-row helpers
// ---------------------------------------------------------------------------
__device__ __forceinline__ void load_row(const float* __restrict__ xr, int lane,
                                         float re[4][4], float im[4][4]) {
#pragma unroll
    for (int j = 0; j < 4; ++j) {
        const float4 r4 = *(const float4*)(xr + j * 256 + lane * 4);
        const float4 i4 = *(const float4*)(xr + DIMQ + j * 256 + lane * 4);
        re[j][0] = r4.x; re[j][1] = r4.y; re[j][2] = r4.z; re[j][3] = r4.w;
        im[j][0] = i4.x; im[j][1] = i4.y; im[j][2] = i4.z; im[j][3] = i4.w;
    }
}

__device__ __forceinline__ void store_row(float* __restrict__ orow, int lane,
                                          float re[4][4], float im[4][4]) {
#pragma unroll
    for (int j = 0; j < 4; ++j) {
        f32x4 r4 = {re[j][0], re[j][1], re[j][2], re[j][3]};
        f32x4 i4 = {im[j][0], im[j][1], im[j][2], im[j][3]};
        __builtin_nontemporal_store(r4, (f32x4*)(orow + j * 256 + lane * 4));
        __builtin_nontemporal_store(i4, (f32x4*)(orow + DIMQ + j * 256 + lane * 4));
    }
}

template <bool USE_WS>
__device__ __forceinline__ void process_row(float re[4][4], float im[4][4], int lane,
                                            const float2* __restrict__ diag,
                                            const float* __restrict__ alphas,
                                            const float* __restrict__ betas,
                                            const float* __restrict__ thetas,
                                            const float* __restrict__ phis,
                                            bool p16ok, bool p32ok) {
    if (USE_WS) diag_apply_ws(re, im, lane, diag);
    else        diag_apply_inline(re, im, lane, alphas, betas, 1.0f);
    bs_transform(re, im, p16ok, p32ok);
    if (USE_WS) diag_apply_ws(re, im, lane, diag + DIMQ);
    else        diag_apply_inline(re, im, lane, thetas, nullptr, 0.03125f);
    bs_transform(re, im, p16ok, p32ok);
    if (USE_WS) diag_apply_ws(re, im, lane, diag + 2 * DIMQ);
    else        diag_apply_inline(re, im, lane, phis, nullptr, 0.03125f);
}

// ---------------------------------------------------------------------------
// Main kernel: one wave per TWO batch rows, software-pipelined so row1's
// loads are in flight during row0's compute. x/out layout: (B, 2, 1024) f32.
// ---------------------------------------------------------------------------
template <bool USE_WS>
__global__ __launch_bounds__(256)
void qlayer_kernel(const float* __restrict__ x,
                   const float2* __restrict__ diag,
                   const float* __restrict__ alphas, const float* __restrict__ betas,
                   const float* __restrict__ thetas, const float* __restrict__ phis,
                   float* __restrict__ out) {
    const int lane = threadIdx.x & 63;
    const int wv   = threadIdx.x >> 6;
    const int row0 = blockIdx.x * 8 + wv * 2;

    const bool p16ok = detect_pls16((unsigned)lane);
    const bool p32ok = detect_pls32((unsigned)lane);

    const float* __restrict__ xr0 = x + (size_t)row0 * (2 * DIMQ);
    const float* __restrict__ xr1 = xr0 + 2 * DIMQ;
    float* __restrict__ or0       = out + (size_t)row0 * (2 * DIMQ);
    float* __restrict__ or1       = or0 + 2 * DIMQ;

    float re0[4][4], im0[4][4], re1[4][4], im1[4][4];
    // Issue ALL 16 loads before any compute: row1's 8 loads remain in
    // flight under row0's entire compute phase (vmcnt ordering).
    load_row(xr0, lane, re0, im0);
    load_row(xr1, lane, re1, im1);

    process_row<USE_WS>(re0, im0, lane, diag, alphas, betas, thetas, phis, p16ok, p32ok);
    store_row(or0, lane, re0, im0);

    process_row<USE_WS>(re1, im1, lane, diag, alphas, betas, thetas, phis, p16ok, p32ok);
    store_row(or1, lane, re1, im1);
}

extern "C" void kernel_launch(void* const* d_in, const int* in_sizes, int n_in,
                              void* d_out, int out_size, void* d_ws, size_t ws_size,
                              hipStream_t stream) {
    const float* x      = (const float*)d_in[0];
    const float* alphas = (const float*)d_in[1];
    const float* betas  = (const float*)d_in[2];
    const float* thetas = (const float*)d_in[3];
    const float* phis   = (const float*)d_in[4];
    float* out = (float*)d_out;

    const int blocks = BATCH_ROWS / 8;  // 4 waves/block, 2 rows/wave

    if (ws_size >= 3 * DIMQ * sizeof(float2)) {
        float2* ws = (float2*)d_ws;
        qdiag_precompute<<<1, DIMQ, 0, stream>>>(alphas, betas, thetas, phis, ws);
        qlayer_kernel<true><<<blocks, 256, 0, stream>>>(x, ws, alphas, betas, thetas, phis, out);
    } else {
        qlayer_kernel<false><<<blocks, 256, 0, stream>>>(x, nullptr, alphas, betas, thetas, phis, out);
    }
}

// Round 6
// 55.190 us; speedup vs baseline: 1.0584x; 1.0584x over previous
//
#include <hip/hip_runtime.h>
#include <math.h>

#define NQ   10
#define DIMQ 1024
#define BATCH_ROWS 16384

typedef unsigned uv2 __attribute__((ext_vector_type(2)));
typedef float f32x4 __attribute__((ext_vector_type(4)));

#if __has_builtin(__builtin_amdgcn_permlane32_swap)
#define HAS_PLS32 1
#else
#define HAS_PLS32 0
#endif
#if __has_builtin(__builtin_amdgcn_permlane16_swap)
#define HAS_PLS16 1
#else
#define HAS_PLS16 0
#endif

// ---------------------------------------------------------------------------
// Precompute: one fused 2x2 complex matrix per qubit.
//   M_k = D(phi)*BS*D(theta)*BS*D(alpha,beta), BS=(1/sqrt2)[[1,i],[i,1]]
//   = 0.5*[[p*u*(t-1), p*v*i(t+1)], [u*i(t+1), v*(1-t)]]
// with u=e^{ia}, v=e^{ib}, t=e^{it}, p=e^{iphi}.
// Stored by STAGE index b (element bit b uses qubit q=9-b), 8 floats each:
//   {m00r,m00i, m01r,m01i, m10r,m10i, m11r,m11i}
// ---------------------------------------------------------------------------
__device__ __forceinline__ float2 cmulc(float2 a, float2 b) {
    return make_float2(a.x * b.x - a.y * b.y, a.x * b.y + a.y * b.x);
}

__global__ void qmat_precompute(const float* __restrict__ alphas,
                                const float* __restrict__ betas,
                                const float* __restrict__ thetas,
                                const float* __restrict__ phis,
                                float* __restrict__ M) {
    const int b = threadIdx.x;
    if (b >= NQ) return;
    const int q = NQ - 1 - b;
    float sa, ca, sb, cb, st, ct, sp, cp;
    sincosf(alphas[q], &sa, &ca);
    sincosf(betas[q],  &sb, &cb);
    sincosf(thetas[q], &st, &ct);
    sincosf(phis[q],   &sp, &cp);
    const float2 u = make_float2(ca, sa), v = make_float2(cb, sb), p = make_float2(cp, sp);
    const float2 tm1  = make_float2(ct - 1.f, st);    // t-1
    const float2 itp1 = make_float2(-st, ct + 1.f);   // i(t+1)
    const float2 omt  = make_float2(1.f - ct, -st);   // 1-t
    float2 m00 = cmulc(cmulc(p, u), tm1);
    float2 m01 = cmulc(cmulc(p, v), itp1);
    float2 m10 = cmulc(u, itp1);
    float2 m11 = cmulc(v, omt);
    const float s = 0.5f;
    M[b * 8 + 0] = m00.x * s; M[b * 8 + 1] = m00.y * s;
    M[b * 8 + 2] = m01.x * s; M[b * 8 + 3] = m01.y * s;
    M[b * 8 + 4] = m10.x * s; M[b * 8 + 5] = m10.y * s;
    M[b * 8 + 6] = m11.x * s; M[b * 8 + 7] = m11.y * s;
}

// ---------------------------------------------------------------------------
// Cross-lane primitives
// ---------------------------------------------------------------------------
template <int CTRL>
__device__ __forceinline__ float dpp_mov(float x) {
    return __int_as_float(
        __builtin_amdgcn_update_dpp(0, __float_as_int(x), CTRL, 0xF, 0xF, true));
}
template <int PAT>
__device__ __forceinline__ float ds_swz(float x) {
    return __int_as_float(__builtin_amdgcn_ds_swizzle(__float_as_int(x), PAT));
}
#define DPP_XOR1 0xB1
#define DPP_XOR2 0x4E
#define SWZ_XOR4 0x101F
#define SWZ_XOR8 0x201F

// orientation: 2 = A, 1 = B, 0 = unknown
__device__ __forceinline__ int orient_pls32(unsigned lane) {
#if HAS_PLS32
    uv2 r = __builtin_amdgcn_permlane32_swap(lane, 1000u + lane, false, false);
    const bool lo = lane < 32;
    unsigned ax = lo ? lane : (1000u + lane - 32u);
    unsigned ay = lo ? (lane + 32u) : (1000u + lane);
    unsigned bx = lo ? (1000u + lane + 32u) : lane;
    unsigned by = lo ? (1000u + lane) : (lane - 32u);
    if (__all(r.x == ax && r.y == ay)) return 2;
    if (__all(r.x == bx && r.y == by)) return 1;
#endif
    return 0;
}
__device__ __forceinline__ int orient_pls16(unsigned lane) {
#if HAS_PLS16
    uv2 r = __builtin_amdgcn_permlane16_swap(lane, 1000u + lane, false, false);
    const bool hi = (lane & 16u) != 0u;
    unsigned ax = hi ? (1000u + lane - 16u) : lane;
    unsigned ay = hi ? (1000u + lane) : (lane + 16u);
    unsigned bx = hi ? lane : (1000u + lane + 16u);
    unsigned by = hi ? (lane - 16u) : (1000u + lane);
    if (__all(r.x == ax && r.y == ay)) return 2;
    if (__all(r.x == bx && r.y == by)) return 1;
#endif
    return 0;
}

// ---------------------------------------------------------------------------
// Stage helpers. Matrix (m0..m7) = (m00r,m00i,m01r,m01i,m10r,m10i,m11r,m11i).
// ---------------------------------------------------------------------------
// Full 2x2 on an in-register pair (a = bit=0 element, b = bit=1 element).
__device__ __forceinline__ void reg_mstage(float& ar, float& ai, float& br, float& bi,
                                           float m0, float m1, float m2, float m3,
                                           float m4, float m5, float m6, float m7) {
    float nar = m0 * ar - m1 * ai + m2 * br - m3 * bi;
    float nai = m0 * ai + m1 * ar + m2 * bi + m3 * br;
    float nbr = m4 * ar - m5 * ai + m6 * br - m7 * bi;
    float nbi = m4 * ai + m5 * ar + m6 * bi + m7 * br;
    ar = nar; ai = nai; br = nbr; bi = nbi;
}

// Fetch-based lane stage: per-lane constants c0 (self) and c1 (partner).
template <class F>
__device__ __forceinline__ void fetch_mstage(float re[4][4], float im[4][4],
                                             float c0r, float c0i, float c1r, float c1i,
                                             F fetch) {
#pragma unroll
    for (int j = 0; j < 4; ++j)
#pragma unroll
        for (int l = 0; l < 4; ++l) {
            const float r = re[j][l], i = im[j][l];
            const float pr = fetch(r), pi = fetch(i);
            re[j][l] = c0r * r - c0i * i + c1r * pr - c1i * pi;
            im[j][l] = c0r * i + c0i * r + c1r * pi + c1i * pr;
        }
}

// permlane-swap lane stage on two register elements f,g (wave-uniform consts).
// Orientation-A: A1 = m00*x + m01*y, A2 = m10*x + m11*y; (f',g') = S(A1,A2).
// Orientation-B: A1 = m11*x + m10*y, A2 = m01*x + m00*y; (f',g') = S(A1,A2).
#if HAS_PLS32
__device__ __forceinline__ void pls32_mstage(float& fr, float& fi, float& gr, float& gi,
                                             float m0, float m1, float m2, float m3,
                                             float m4, float m5, float m6, float m7,
                                             bool orientA) {
    uv2 sr = __builtin_amdgcn_permlane32_swap(__float_as_uint(fr), __float_as_uint(gr), false, false);
    uv2 si = __builtin_amdgcn_permlane32_swap(__float_as_uint(fi), __float_as_uint(gi), false, false);
    const float pxr = __uint_as_float(sr.x), pyr = __uint_as_float(sr.y);
    const float pxi = __uint_as_float(si.x), pyi = __uint_as_float(si.y);
    float A1r, A1i, A2r, A2i;
    if (orientA) {
        A1r = m0 * pxr - m1 * pxi + m2 * pyr - m3 * pyi;
        A1i = m0 * pxi + m1 * pxr + m2 * pyi + m3 * pyr;
        A2r = m4 * pxr - m5 * pxi + m6 * pyr - m7 * pyi;
        A2i = m4 * pxi + m5 * pxr + m6 * pyi + m7 * pyr;
    } else {
        A1r = m6 * pxr - m7 * pxi + m4 * pyr - m5 * pyi;
        A1i = m6 * pxi + m7 * pxr + m4 * pyi + m5 * pyr;
        A2r = m2 * pxr - m3 * pxi + m0 * pyr - m1 * pyi;
        A2i = m2 * pxi + m3 * pxr + m0 * pyi + m1 * pyr;
    }
    uv2 rr = __builtin_amdgcn_permlane32_swap(__float_as_uint(A1r), __float_as_uint(A2r), false, false);
    uv2 ri = __builtin_amdgcn_permlane32_swap(__float_as_uint(A1i), __float_as_uint(A2i), false, false);
    fr = __uint_as_float(rr.x); gr = __uint_as_float(rr.y);
    fi = __uint_as_float(ri.x); gi = __uint_as_float(ri.y);
}
#endif
#if HAS_PLS16
__device__ __forceinline__ void pls16_mstage(float& fr, float& fi, float& gr, float& gi,
                                             float m0, float m1, float m2, float m3,
                                             float m4, float m5, float m6, float m7,
                                             bool orientA) {
    uv2 sr = __builtin_amdgcn_permlane16_swap(__float_as_uint(fr), __float_as_uint(gr), false, false);
    uv2 si = __builtin_amdgcn_permlane16_swap(__float_as_uint(fi), __float_as_uint(gi), false, false);
    const float pxr = __uint_as_float(sr.x), pyr = __uint_as_float(sr.y);
    const float pxi = __uint_as_float(si.x), pyi = __uint_as_float(si.y);
    float A1r, A1i, A2r, A2i;
    if (orientA) {
        A1r = m0 * pxr - m1 * pxi + m2 * pyr - m3 * pyi;
        A1i = m0 * pxi + m1 * pxr + m2 * pyi + m3 * pyr;
        A2r = m4 * pxr - m5 * pxi + m6 * pyr - m7 * pyi;
        A2i = m4 * pxi + m5 * pxr + m6 * pyi + m7 * pyr;
    } else {
        A1r = m6 * pxr - m7 * pxi + m4 * pyr - m5 * pyi;
        A1i = m6 * pxi + m7 * pxr + m4 * pyi + m5 * pyr;
        A2r = m2 * pxr - m3 * pxi + m0 * pyr - m1 * pyi;
        A2i = m2 * pxi + m3 * pxr + m0 * pyi + m1 * pyr;
    }
    uv2 rr = __builtin_amdgcn_permlane16_swap(__float_as_uint(A1r), __float_as_uint(A2r), false, false);
    uv2 ri = __builtin_amdgcn_permlane16_swap(__float_as_uint(A1i), __float_as_uint(A2i), false, false);
    fr = __uint_as_float(rr.x); gr = __uint_as_float(rr.y);
    fi = __uint_as_float(ri.x); gi = __uint_as_float(ri.y);
}
#endif

// ---------------------------------------------------------------------------
// Main fused kernel: one wave per batch row; element e = j*256 + lane*4 + l.
// 10 commuting stages: bit0,bit1 (reg l) -> masks 1,2 (DPP) -> masks 4,8 (DS)
// -> masks 16,32 (permlane-swap) -> bit8,bit9 (reg j).
// ---------------------------------------------------------------------------
template <bool USE_WS>
__global__ __launch_bounds__(256)
void qlayer_fused(const float* __restrict__ x, const float* __restrict__ Mtab,
                  const float* __restrict__ alphas, const float* __restrict__ betas,
                  const float* __restrict__ thetas, const float* __restrict__ phis,
                  float* __restrict__ out) {
    const int lane = threadIdx.x & 63;
    const int wv   = threadIdx.x >> 6;
    const int row  = blockIdx.x * 4 + wv;

    const int o16 = orient_pls16((unsigned)lane);
    const int o32 = orient_pls32((unsigned)lane);

    const float* __restrict__ xr = x + (size_t)row * (2 * DIMQ);
    float* __restrict__ orow     = out + (size_t)row * (2 * DIMQ);

    // Fallback path: compute M per-thread (identical values in all lanes).
    float Ml[NQ * 8];
    if (!USE_WS) {
#pragma unroll
        for (int b = 0; b < NQ; ++b) {
            const int q = NQ - 1 - b;
            float sa, ca, sb, cb, st, ct, sp, cp;
            sincosf(alphas[q], &sa, &ca);
            sincosf(betas[q],  &sb, &cb);
            sincosf(thetas[q], &st, &ct);
            sincosf(phis[q],   &sp, &cp);
            const float2 u = make_float2(ca, sa), v = make_float2(cb, sb), p = make_float2(cp, sp);
            const float2 tm1  = make_float2(ct - 1.f, st);
            const float2 itp1 = make_float2(-st, ct + 1.f);
            const float2 omt  = make_float2(1.f - ct, -st);
            float2 m00 = cmulc(cmulc(p, u), tm1);
            float2 m01 = cmulc(cmulc(p, v), itp1);
            float2 m10 = cmulc(u, itp1);
            float2 m11 = cmulc(v, omt);
            Ml[b * 8 + 0] = m00.x * .5f; Ml[b * 8 + 1] = m00.y * .5f;
            Ml[b * 8 + 2] = m01.x * .5f; Ml[b * 8 + 3] = m01.y * .5f;
            Ml[b * 8 + 4] = m10.x * .5f; Ml[b * 8 + 5] = m10.y * .5f;
            Ml[b * 8 + 6] = m11.x * .5f; Ml[b * 8 + 7] = m11.y * .5f;
        }
    }

    float re[4][4], im[4][4];
#pragma unroll
    for (int j = 0; j < 4; ++j) {
        const float4 r4 = *(const float4*)(xr + j * 256 + lane * 4);
        const float4 i4 = *(const float4*)(xr + DIMQ + j * 256 + lane * 4);
        re[j][0] = r4.x; re[j][1] = r4.y; re[j][2] = r4.z; re[j][3] = r4.w;
        im[j][0] = i4.x; im[j][1] = i4.y; im[j][2] = i4.z; im[j][3] = i4.w;
    }

    float m0, m1, m2, m3, m4, m5, m6, m7;
#define LOADM(s_) do {                                                     \
    if (USE_WS) {                                                          \
        m0 = Mtab[(s_) * 8 + 0]; m1 = Mtab[(s_) * 8 + 1];                  \
        m2 = Mtab[(s_) * 8 + 2]; m3 = Mtab[(s_) * 8 + 3];                  \
        m4 = Mtab[(s_) * 8 + 4]; m5 = Mtab[(s_) * 8 + 5];                  \
        m6 = Mtab[(s_) * 8 + 6]; m7 = Mtab[(s_) * 8 + 7];                  \
    } else {                                                               \
        m0 = Ml[(s_) * 8 + 0]; m1 = Ml[(s_) * 8 + 1];                      \
        m2 = Ml[(s_) * 8 + 2]; m3 = Ml[(s_) * 8 + 3];                      \
        m4 = Ml[(s_) * 8 + 4]; m5 = Ml[(s_) * 8 + 5];                      \
        m6 = Ml[(s_) * 8 + 6]; m7 = Ml[(s_) * 8 + 7];                      \
    }                                                                      \
} while (0)
#define SELC(maskbit) \
    const bool hb = (lane & (maskbit)) != 0;                               \
    const float c0r = hb ? m6 : m0, c0i = hb ? m7 : m1;                    \
    const float c1r = hb ? m4 : m2, c1i = hb ? m5 : m3;

    // stage 0: element bit0 (register pairs l^1)
    LOADM(0);
#pragma unroll
    for (int j = 0; j < 4; ++j) {
        reg_mstage(re[j][0], im[j][0], re[j][1], im[j][1], m0, m1, m2, m3, m4, m5, m6, m7);
        reg_mstage(re[j][2], im[j][2], re[j][3], im[j][3], m0, m1, m2, m3, m4, m5, m6, m7);
    }
    // stage 1: element bit1 (register pairs l^2)
    LOADM(1);
#pragma unroll
    for (int j = 0; j < 4; ++j) {
        reg_mstage(re[j][0], im[j][0], re[j][2], im[j][2], m0, m1, m2, m3, m4, m5, m6, m7);
        reg_mstage(re[j][1], im[j][1], re[j][3], im[j][3], m0, m1, m2, m3, m4, m5, m6, m7);
    }
    // stage 2: lane mask 1 (DPP)
    {
        LOADM(2);
        SELC(1);
        fetch_mstage(re, im, c0r, c0i, c1r, c1i,
                     [](float v) { return dpp_mov<DPP_XOR1>(v); });
    }
    // stage 3: lane mask 2 (DPP)
    {
        LOADM(3);
        SELC(2);
        fetch_mstage(re, im, c0r, c0i, c1r, c1i,
                     [](float v) { return dpp_mov<DPP_XOR2>(v); });
    }
    // stage 4: lane mask 4 (ds_swizzle)
    {
        LOADM(4);
        SELC(4);
        fetch_mstage(re, im, c0r, c0i, c1r, c1i,
                     [](float v) { return ds_swz<SWZ_XOR4>(v); });
    }
    // stage 5: lane mask 8 (ds_swizzle)
    {
        LOADM(5);
        SELC(8);
        fetch_mstage(re, im, c0r, c0i, c1r, c1i,
                     [](float v) { return ds_swz<SWZ_XOR8>(v); });
    }
    // stage 6: lane mask 16 (permlane16_swap, wave-uniform consts)
    {
        LOADM(6);
#if HAS_PLS16
        if (o16 != 0) {
            const bool oA = (o16 == 2);
#pragma unroll
            for (int j = 0; j < 4; ++j) {
                pls16_mstage(re[j][0], im[j][0], re[j][1], im[j][1], m0, m1, m2, m3, m4, m5, m6, m7, oA);
                pls16_mstage(re[j][2], im[j][2], re[j][3], im[j][3], m0, m1, m2, m3, m4, m5, m6, m7, oA);
            }
        } else
#endif
        {
            SELC(16);
            fetch_mstage(re, im, c0r, c0i, c1r, c1i,
                         [](float v) { return __shfl_xor(v, 16, 64); });
        }
    }
    // stage 7: lane mask 32 (permlane32_swap, wave-uniform consts)
    {
        LOADM(7);
#if HAS_PLS32
        if (o32 != 0) {
            const bool oA = (o32 == 2);
#pragma unroll
            for (int j = 0; j < 4; ++j) {
                pls32_mstage(re[j][0], im[j][0], re[j][1], im[j][1], m0, m1, m2, m3, m4, m5, m6, m7, oA);
                pls32_mstage(re[j][2], im[j][2], re[j][3], im[j][3], m0, m1, m2, m3, m4, m5, m6, m7, oA);
            }
        } else
#endif
        {
            SELC(32);
            fetch_mstage(re, im, c0r, c0i, c1r, c1i,
                         [](float v) { return __shfl_xor(v, 32, 64); });
        }
    }
    // stage 8: element bit8 (register pairs j^1)
    LOADM(8);
#pragma unroll
    for (int l = 0; l < 4; ++l) {
        reg_mstage(re[0][l], im[0][l], re[1][l], im[1][l], m0, m1, m2, m3, m4, m5, m6, m7);
        reg_mstage(re[2][l], im[2][l], re[3][l], im[3][l], m0, m1, m2, m3, m4, m5, m6, m7);
    }
    // stage 9: element bit9 (register pairs j^2)
    LOADM(9);
#pragma unroll
    for (int l = 0; l < 4; ++l) {
        reg_mstage(re[0][l], im[0][l], re[2][l], im[2][l], m0, m1, m2, m3, m4, m5, m6, m7);
        reg_mstage(re[1][l], im[1][l], re[3][l], im[3][l], m0, m1, m2, m3, m4, m5, m6, m7);
    }
#undef LOADM
#undef SELC

    // Nontemporal stores: output is never re-read.
#pragma unroll
    for (int j = 0; j < 4; ++j) {
        f32x4 r4 = {re[j][0], re[j][1], re[j][2], re[j][3]};
        f32x4 i4 = {im[j][0], im[j][1], im[j][2], im[j][3]};
        __builtin_nontemporal_store(r4, (f32x4*)(orow + j * 256 + lane * 4));
        __builtin_nontemporal_store(i4, (f32x4*)(orow + DIMQ + j * 256 + lane * 4));
    }
}

extern "C" void kernel_launch(void* const* d_in, const int* in_sizes, int n_in,
                              void* d_out, int out_size, void* d_ws, size_t ws_size,
                              hipStream_t stream) {
    const float* x      = (const float*)d_in[0];
    const float* alphas = (const float*)d_in[1];
    const float* betas  = (const float*)d_in[2];
    const float* thetas = (const float*)d_in[3];
    const float* phis   = (const float*)d_in[4];
    float* out = (float*)d_out;

    const int blocks = BATCH_ROWS / 4;  // 4 waves (rows) per 256-thread block

    if (ws_size >= NQ * 8 * sizeof(float)) {
        float* M = (float*)d_ws;
        qmat_precompute<<<1, 64, 0, stream>>>(alphas, betas, thetas, phis, M);
        qlayer_fused<true><<<blocks, 256, 0, stream>>>(x, M, alphas, betas, thetas, phis, out);
    } else {
        qlayer_fused<false><<<blocks, 256, 0, stream>>>(x, nullptr, alphas, betas, thetas, phis, out);
    }
}

// Round 7
// 54.235 us; speedup vs baseline: 1.0770x; 1.0176x over previous
//
#include <hip/hip_runtime.h>
#include <math.h>

#define NQ   10
#define DIMQ 1024
#define BATCH_ROWS 16384

typedef unsigned uv2 __attribute__((ext_vector_type(2)));
typedef float f32x2 __attribute__((ext_vector_type(2)));
typedef float f32x4 __attribute__((ext_vector_type(4)));

#if __has_builtin(__builtin_amdgcn_permlane32_swap)
#define HAS_PLS32 1
#else
#define HAS_PLS32 0
#endif
#if __has_builtin(__builtin_amdgcn_permlane16_swap)
#define HAS_PLS16 1
#else
#define HAS_PLS16 0
#endif

// ---------------------------------------------------------------------------
// Precompute: one fused 2x2 complex matrix per qubit (validated in R6).
//   M_k = D(phi)*BS*D(theta)*BS*D(alpha,beta)
//   = 0.5*[[p*u*(t-1), p*v*i(t+1)], [u*i(t+1), v*(1-t)]]
// Stored by STAGE index b (element bit b uses qubit q=9-b).
// ---------------------------------------------------------------------------
__device__ __forceinline__ float2 cmulc(float2 a, float2 b) {
    return make_float2(a.x * b.x - a.y * b.y, a.x * b.y + a.y * b.x);
}

__global__ void qmat_precompute(const float* __restrict__ alphas,
                                const float* __restrict__ betas,
                                const float* __restrict__ thetas,
                                const float* __restrict__ phis,
                                float* __restrict__ M) {
    const int b = threadIdx.x;
    if (b >= NQ) return;
    const int q = NQ - 1 - b;
    float sa, ca, sb, cb, st, ct, sp, cp;
    sincosf(alphas[q], &sa, &ca);
    sincosf(betas[q],  &sb, &cb);
    sincosf(thetas[q], &st, &ct);
    sincosf(phis[q],   &sp, &cp);
    const float2 u = make_float2(ca, sa), v = make_float2(cb, sb), p = make_float2(cp, sp);
    const float2 tm1  = make_float2(ct - 1.f, st);
    const float2 itp1 = make_float2(-st, ct + 1.f);
    const float2 omt  = make_float2(1.f - ct, -st);
    float2 m00 = cmulc(cmulc(p, u), tm1);
    float2 m01 = cmulc(cmulc(p, v), itp1);
    float2 m10 = cmulc(u, itp1);
    float2 m11 = cmulc(v, omt);
    const float s = 0.5f;
    M[b * 8 + 0] = m00.x * s; M[b * 8 + 1] = m00.y * s;
    M[b * 8 + 2] = m01.x * s; M[b * 8 + 3] = m01.y * s;
    M[b * 8 + 4] = m10.x * s; M[b * 8 + 5] = m10.y * s;
    M[b * 8 + 6] = m11.x * s; M[b * 8 + 7] = m11.y * s;
}

// ---------------------------------------------------------------------------
// Cross-lane primitives (scalar + packed wrappers)
// ---------------------------------------------------------------------------
template <int CTRL>
__device__ __forceinline__ float dpp_mov(float x) {
    return __int_as_float(
        __builtin_amdgcn_update_dpp(0, __float_as_int(x), CTRL, 0xF, 0xF, true));
}
template <int PAT>
__device__ __forceinline__ float ds_swz(float x) {
    return __int_as_float(__builtin_amdgcn_ds_swizzle(__float_as_int(x), PAT));
}
template <int CTRL>
__device__ __forceinline__ f32x2 pk_dpp(f32x2 v) {
    return (f32x2){dpp_mov<CTRL>(v.x), dpp_mov<CTRL>(v.y)};
}
template <int PAT>
__device__ __forceinline__ f32x2 pk_swz(f32x2 v) {
    return (f32x2){ds_swz<PAT>(v.x), ds_swz<PAT>(v.y)};
}
__device__ __forceinline__ f32x2 pk_shfl_xor(f32x2 v, int m) {
    return (f32x2){__shfl_xor(v.x, m, 64), __shfl_xor(v.y, m, 64)};
}
__device__ __forceinline__ f32x2 pk_swap(f32x2 v) { return (f32x2){v.y, v.x}; }

#define DPP_XOR1 0xB1
#define DPP_XOR2 0x4E
#define SWZ_XOR4 0x101F
#define SWZ_XOR8 0x201F

// orientation: 2 = A, 1 = B, 0 = unknown (shfl fallback)
__device__ __forceinline__ int orient_pls32(unsigned lane) {
#if HAS_PLS32
    uv2 r = __builtin_amdgcn_permlane32_swap(lane, 1000u + lane, false, false);
    const bool lo = lane < 32;
    unsigned ax = lo ? lane : (1000u + lane - 32u);
    unsigned ay = lo ? (lane + 32u) : (1000u + lane);
    unsigned bx = lo ? (1000u + lane + 32u) : lane;
    unsigned by = lo ? (1000u + lane) : (lane - 32u);
    if (__all(r.x == ax && r.y == ay)) return 2;
    if (__all(r.x == bx && r.y == by)) return 1;
#endif
    return 0;
}
__device__ __forceinline__ int orient_pls16(unsigned lane) {
#if HAS_PLS16
    uv2 r = __builtin_amdgcn_permlane16_swap(lane, 1000u + lane, false, false);
    const bool hi = (lane & 16u) != 0u;
    unsigned ax = hi ? (1000u + lane - 16u) : lane;
    unsigned ay = hi ? (1000u + lane) : (lane + 16u);
    unsigned bx = hi ? lane : (1000u + lane + 16u);
    unsigned by = hi ? (lane - 16u) : (1000u + lane);
    if (__all(r.x == ax && r.y == ay)) return 2;
    if (__all(r.x == bx && r.y == by)) return 1;
#endif
    return 0;
}

// ---------------------------------------------------------------------------
// Packed stage helpers. (m0..m7) = (m00r,m00i,m01r,m01i,m10r,m10i,m11r,m11i).
// Each f32x2 carries two independent j-problems -> v_pk_* math.
// ---------------------------------------------------------------------------
__device__ __forceinline__ void pk_mstage(f32x2& ar, f32x2& ai, f32x2& br, f32x2& bi,
                                          float m0, float m1, float m2, float m3,
                                          float m4, float m5, float m6, float m7) {
    f32x2 nar = m0 * ar - m1 * ai + m2 * br - m3 * bi;
    f32x2 nai = m0 * ai + m1 * ar + m2 * bi + m3 * br;
    f32x2 nbr = m4 * ar - m5 * ai + m6 * br - m7 * bi;
    f32x2 nbi = m4 * ai + m5 * ar + m6 * bi + m7 * br;
    ar = nar; ai = nai; br = nbr; bi = nbi;
}

// Fetch-based lane stage: per-lane scalar consts broadcast across the pack.
template <class F>
__device__ __forceinline__ void pk_fetch_stage(f32x2 re[2][4], f32x2 im[2][4],
                                               float c0r, float c0i, float c1r, float c1i,
                                               F fetch) {
#pragma unroll
    for (int p = 0; p < 2; ++p)
#pragma unroll
        for (int l = 0; l < 4; ++l) {
            const f32x2 r = re[p][l], i = im[p][l];
            const f32x2 pr = fetch(r), pi = fetch(i);
            re[p][l] = c0r * r - c0i * i + c1r * pr - c1i * pi;
            im[p][l] = c0r * i + c0i * r + c1r * pi + c1i * pr;
        }
}

#if HAS_PLS32
__device__ __forceinline__ void pk_pls32_mstage(f32x2& fr, f32x2& fi, f32x2& gr, f32x2& gi,
                                                float m0, float m1, float m2, float m3,
                                                float m4, float m5, float m6, float m7,
                                                bool orientA) {
    uv2 rx = __builtin_amdgcn_permlane32_swap(__float_as_uint(fr.x), __float_as_uint(gr.x), false, false);
    uv2 ry = __builtin_amdgcn_permlane32_swap(__float_as_uint(fr.y), __float_as_uint(gr.y), false, false);
    uv2 ix = __builtin_amdgcn_permlane32_swap(__float_as_uint(fi.x), __float_as_uint(gi.x), false, false);
    uv2 iy = __builtin_amdgcn_permlane32_swap(__float_as_uint(fi.y), __float_as_uint(gi.y), false, false);
    f32x2 pxr = {__uint_as_float(rx.x), __uint_as_float(ry.x)};
    f32x2 pyr = {__uint_as_float(rx.y), __uint_as_float(ry.y)};
    f32x2 pxi = {__uint_as_float(ix.x), __uint_as_float(iy.x)};
    f32x2 pyi = {__uint_as_float(ix.y), __uint_as_float(iy.y)};
    f32x2 A1r, A1i, A2r, A2i;
    if (orientA) {
        A1r = m0 * pxr - m1 * pxi + m2 * pyr - m3 * pyi;
        A1i = m0 * pxi + m1 * pxr + m2 * pyi + m3 * pyr;
        A2r = m4 * pxr - m5 * pxi + m6 * pyr - m7 * pyi;
        A2i = m4 * pxi + m5 * pxr + m6 * pyi + m7 * pyr;
    } else {
        A1r = m6 * pxr - m7 * pxi + m4 * pyr - m5 * pyi;
        A1i = m6 * pxi + m7 * pxr + m4 * pyi + m5 * pyr;
        A2r = m2 * pxr - m3 * pxi + m0 * pyr - m1 * pyi;
        A2i = m2 * pxi + m3 * pxr + m0 * pyi + m1 * pyr;
    }
    uv2 ox = __builtin_amdgcn_permlane32_swap(__float_as_uint(A1r.x), __float_as_uint(A2r.x), false, false);
    uv2 oy = __builtin_amdgcn_permlane32_swap(__float_as_uint(A1r.y), __float_as_uint(A2r.y), false, false);
    uv2 px = __builtin_amdgcn_permlane32_swap(__float_as_uint(A1i.x), __float_as_uint(A2i.x), false, false);
    uv2 py = __builtin_amdgcn_permlane32_swap(__float_as_uint(A1i.y), __float_as_uint(A2i.y), false, false);
    fr = (f32x2){__uint_as_float(ox.x), __uint_as_float(oy.x)};
    gr = (f32x2){__uint_as_float(ox.y), __uint_as_float(oy.y)};
    fi = (f32x2){__uint_as_float(px.x), __uint_as_float(py.x)};
    gi = (f32x2){__uint_as_float(px.y), __uint_as_float(py.y)};
}
#endif
#if HAS_PLS16
__device__ __forceinline__ void pk_pls16_mstage(f32x2& fr, f32x2& fi, f32x2& gr, f32x2& gi,
                                                float m0, float m1, float m2, float m3,
                                                float m4, float m5, float m6, float m7,
                                                bool orientA) {
    uv2 rx = __builtin_amdgcn_permlane16_swap(__float_as_uint(fr.x), __float_as_uint(gr.x), false, false);
    uv2 ry = __builtin_amdgcn_permlane16_swap(__float_as_uint(fr.y), __float_as_uint(gr.y), false, false);
    uv2 ix = __builtin_amdgcn_permlane16_swap(__float_as_uint(fi.x), __float_as_uint(gi.x), false, false);
    uv2 iy = __builtin_amdgcn_permlane16_swap(__float_as_uint(fi.y), __float_as_uint(gi.y), false, false);
    f32x2 pxr = {__uint_as_float(rx.x), __uint_as_float(ry.x)};
    f32x2 pyr = {__uint_as_float(rx.y), __uint_as_float(ry.y)};
    f32x2 pxi = {__uint_as_float(ix.x), __uint_as_float(iy.x)};
    f32x2 pyi = {__uint_as_float(ix.y), __uint_as_float(iy.y)};
    f32x2 A1r, A1i, A2r, A2i;
    if (orientA) {
        A1r = m0 * pxr - m1 * pxi + m2 * pyr - m3 * pyi;
        A1i = m0 * pxi + m1 * pxr + m2 * pyi + m3 * pyr;
        A2r = m4 * pxr - m5 * pxi + m6 * pyr - m7 * pyi;
        A2i = m4 * pxi + m5 * pxr + m6 * pyi + m7 * pyr;
    } else {
        A1r = m6 * pxr - m7 * pxi + m4 * pyr - m5 * pyi;
        A1i = m6 * pxi + m7 * pxr + m4 * pyi + m5 * pyr;
        A2r = m2 * pxr - m3 * pxi + m0 * pyr - m1 * pyi;
        A2i = m2 * pxi + m3 * pxr + m0 * pyi + m1 * pyr;
    }
    uv2 ox = __builtin_amdgcn_permlane16_swap(__float_as_uint(A1r.x), __float_as_uint(A2r.x), false, false);
    uv2 oy = __builtin_amdgcn_permlane16_swap(__float_as_uint(A1r.y), __float_as_uint(A2r.y), false, false);
    uv2 px = __builtin_amdgcn_permlane16_swap(__float_as_uint(A1i.x), __float_as_uint(A2i.x), false, false);
    uv2 py = __builtin_amdgcn_permlane16_swap(__float_as_uint(A1i.y), __float_as_uint(A2i.y), false, false);
    fr = (f32x2){__uint_as_float(ox.x), __uint_as_float(oy.x)};
    gr = (f32x2){__uint_as_float(ox.y), __uint_as_float(oy.y)};
    fi = (f32x2){__uint_as_float(px.x), __uint_as_float(py.x)};
    gi = (f32x2){__uint_as_float(px.y), __uint_as_float(py.y)};
}
#endif

// ---------------------------------------------------------------------------
// Main fused packed kernel. Element e = j*256 + lane*4 + l; j = 2p + c where
// p = pack index, c = component within f32x2. Stages 0-7 are j-uniform
// (packed with broadcast consts); stage 8 (j^1) packs with split consts +
// component swap; stage 9 (j^2) packs across p.
// ---------------------------------------------------------------------------
template <bool USE_WS>
__global__ __launch_bounds__(256)
void qlayer_fused(const float* __restrict__ x, const float* __restrict__ Mtab,
                  const float* __restrict__ alphas, const float* __restrict__ betas,
                  const float* __restrict__ thetas, const float* __restrict__ phis,
                  float* __restrict__ out) {
    const int lane = threadIdx.x & 63;
    const int wv   = threadIdx.x >> 6;
    const int row  = blockIdx.x * 4 + wv;

    const int o16 = orient_pls16((unsigned)lane);
    const int o32 = orient_pls32((unsigned)lane);

    const float* __restrict__ xr = x + (size_t)row * (2 * DIMQ);
    float* __restrict__ orow     = out + (size_t)row * (2 * DIMQ);

    // Fallback path: compute M per-thread (identical in all lanes).
    float Ml[NQ * 8];
    if (!USE_WS) {
#pragma unroll
        for (int b = 0; b < NQ; ++b) {
            const int q = NQ - 1 - b;
            float sa, ca, sb, cb, st, ct, sp, cp;
            sincosf(alphas[q], &sa, &ca);
            sincosf(betas[q],  &sb, &cb);
            sincosf(thetas[q], &st, &ct);
            sincosf(phis[q],   &sp, &cp);
            const float2 u = make_float2(ca, sa), v = make_float2(cb, sb), p2 = make_float2(cp, sp);
            const float2 tm1  = make_float2(ct - 1.f, st);
            const float2 itp1 = make_float2(-st, ct + 1.f);
            const float2 omt  = make_float2(1.f - ct, -st);
            float2 m00 = cmulc(cmulc(p2, u), tm1);
            float2 m01 = cmulc(cmulc(p2, v), itp1);
            float2 m10 = cmulc(u, itp1);
            float2 m11 = cmulc(v, omt);
            Ml[b * 8 + 0] = m00.x * .5f; Ml[b * 8 + 1] = m00.y * .5f;
            Ml[b * 8 + 2] = m01.x * .5f; Ml[b * 8 + 3] = m01.y * .5f;
            Ml[b * 8 + 4] = m10.x * .5f; Ml[b * 8 + 5] = m10.y * .5f;
            Ml[b * 8 + 6] = m11.x * .5f; Ml[b * 8 + 7] = m11.y * .5f;
        }
    }

    // Load + pack over j-pairs: Pre[p][l] = (re[j=2p][l], re[j=2p+1][l])
    f32x2 Pre[2][4], Pim[2][4];
#pragma unroll
    for (int p = 0; p < 2; ++p) {
        const f32x4 rA = *(const f32x4*)(xr + (2 * p + 0) * 256 + lane * 4);
        const f32x4 iA = *(const f32x4*)(xr + DIMQ + (2 * p + 0) * 256 + lane * 4);
        const f32x4 rB = *(const f32x4*)(xr + (2 * p + 1) * 256 + lane * 4);
        const f32x4 iB = *(const f32x4*)(xr + DIMQ + (2 * p + 1) * 256 + lane * 4);
#pragma unroll
        for (int l = 0; l < 4; ++l) {
            Pre[p][l] = (f32x2){rA[l], rB[l]};
            Pim[p][l] = (f32x2){iA[l], iB[l]};
        }
    }

    float m0, m1, m2, m3, m4, m5, m6, m7;
#define LOADM(s_) do {                                                     \
    if (USE_WS) {                                                          \
        m0 = Mtab[(s_) * 8 + 0]; m1 = Mtab[(s_) * 8 + 1];                  \
        m2 = Mtab[(s_) * 8 + 2]; m3 = Mtab[(s_) * 8 + 3];                  \
        m4 = Mtab[(s_) * 8 + 4]; m5 = Mtab[(s_) * 8 + 5];                  \
        m6 = Mtab[(s_) * 8 + 6]; m7 = Mtab[(s_) * 8 + 7];                  \
    } else {                                                               \
        m0 = Ml[(s_) * 8 + 0]; m1 = Ml[(s_) * 8 + 1];                      \
        m2 = Ml[(s_) * 8 + 2]; m3 = Ml[(s_) * 8 + 3];                      \
        m4 = Ml[(s_) * 8 + 4]; m5 = Ml[(s_) * 8 + 5];                      \
        m6 = Ml[(s_) * 8 + 6]; m7 = Ml[(s_) * 8 + 7];                      \
    }                                                                      \
} while (0)
#define SELC(maskbit) \
    const bool hb = (lane & (maskbit)) != 0;                               \
    const float c0r = hb ? m6 : m0, c0i = hb ? m7 : m1;                    \
    const float c1r = hb ? m4 : m2, c1i = hb ? m5 : m3;

    // stage 0: element bit0 (register pairs l^1)
    LOADM(0);
#pragma unroll
    for (int p = 0; p < 2; ++p) {
        pk_mstage(Pre[p][0], Pim[p][0], Pre[p][1], Pim[p][1], m0, m1, m2, m3, m4, m5, m6, m7);
        pk_mstage(Pre[p][2], Pim[p][2], Pre[p][3], Pim[p][3], m0, m1, m2, m3, m4, m5, m6, m7);
    }
    // stage 1: element bit1 (register pairs l^2)
    LOADM(1);
#pragma unroll
    for (int p = 0; p < 2; ++p) {
        pk_mstage(Pre[p][0], Pim[p][0], Pre[p][2], Pim[p][2], m0, m1, m2, m3, m4, m5, m6, m7);
        pk_mstage(Pre[p][1], Pim[p][1], Pre[p][3], Pim[p][3], m0, m1, m2, m3, m4, m5, m6, m7);
    }
    // stage 2: lane mask 1 (DPP)
    {
        LOADM(2);
        SELC(1);
        pk_fetch_stage(Pre, Pim, c0r, c0i, c1r, c1i,
                       [](f32x2 v) { return pk_dpp<DPP_XOR1>(v); });
    }
    // stage 3: lane mask 2 (DPP)
    {
        LOADM(3);
        SELC(2);
        pk_fetch_stage(Pre, Pim, c0r, c0i, c1r, c1i,
                       [](f32x2 v) { return pk_dpp<DPP_XOR2>(v); });
    }
    // stage 4: lane mask 4 (ds_swizzle)
    {
        LOADM(4);
        SELC(4);
        pk_fetch_stage(Pre, Pim, c0r, c0i, c1r, c1i,
                       [](f32x2 v) { return pk_swz<SWZ_XOR4>(v); });
    }
    // stage 5: lane mask 8 (ds_swizzle)
    {
        LOADM(5);
        SELC(8);
        pk_fetch_stage(Pre, Pim, c0r, c0i, c1r, c1i,
                       [](f32x2 v) { return pk_swz<SWZ_XOR8>(v); });
    }
    // stage 6: lane mask 16 (permlane16_swap, wave-uniform consts)
    {
        LOADM(6);
#if HAS_PLS16
        if (o16 != 0) {
            const bool oA = (o16 == 2);
#pragma unroll
            for (int p = 0; p < 2; ++p) {
                pk_pls16_mstage(Pre[p][0], Pim[p][0], Pre[p][1], Pim[p][1], m0, m1, m2, m3, m4, m5, m6, m7, oA);
                pk_pls16_mstage(Pre[p][2], Pim[p][2], Pre[p][3], Pim[p][3], m0, m1, m2, m3, m4, m5, m6, m7, oA);
            }
        } else
#endif
        {
            SELC(16);
            pk_fetch_stage(Pre, Pim, c0r, c0i, c1r, c1i,
                           [](f32x2 v) { return pk_shfl_xor(v, 16); });
        }
    }
    // stage 7: lane mask 32 (permlane32_swap, wave-uniform consts)
    {
        LOADM(7);
#if HAS_PLS32
        if (o32 != 0) {
            const bool oA = (o32 == 2);
#pragma unroll
            for (int p = 0; p < 2; ++p) {
                pk_pls32_mstage(Pre[p][0], Pim[p][0], Pre[p][1], Pim[p][1], m0, m1, m2, m3, m4, m5, m6, m7, oA);
                pk_pls32_mstage(Pre[p][2], Pim[p][2], Pre[p][3], Pim[p][3], m0, m1, m2, m3, m4, m5, m6, m7, oA);
            }
        } else
#endif
        {
            SELC(32);
            pk_fetch_stage(Pre, Pim, c0r, c0i, c1r, c1i,
                           [](f32x2 v) { return pk_shfl_xor(v, 32); });
        }
    }
    // stage 8: element bit8 (j^1 = intra-pack). Component-split consts:
    // new_re = {m0,m6}*re - {m1,m7}*im + {m2,m4}*Sre - {m3,m5}*Sim
    {
        LOADM(8);
        const f32x2 csr = {m0, m6}, csi = {m1, m7};
        const f32x2 cor = {m2, m4}, coi = {m3, m5};
#pragma unroll
        for (int p = 0; p < 2; ++p)
#pragma unroll
            for (int l = 0; l < 4; ++l) {
                const f32x2 r = Pre[p][l], i = Pim[p][l];
                const f32x2 Sr = pk_swap(r), Si = pk_swap(i);
                Pre[p][l] = csr * r - csi * i + cor * Sr - coi * Si;
                Pim[p][l] = csr * i + csi * r + cor * Si + coi * Sr;
            }
    }
    // stage 9: element bit9 (j^2 = across packs), fully packed
    LOADM(9);
#pragma unroll
    for (int l = 0; l < 4; ++l)
        pk_mstage(Pre[0][l], Pim[0][l], Pre[1][l], Pim[1][l], m0, m1, m2, m3, m4, m5, m6, m7);
#undef LOADM
#undef SELC

    // Unpack + nontemporal stores (output never re-read).
#pragma unroll
    for (int p = 0; p < 2; ++p)
#pragma unroll
        for (int c = 0; c < 2; ++c) {
            const int j = 2 * p + c;
            f32x4 r4 = {Pre[p][0][c], Pre[p][1][c], Pre[p][2][c], Pre[p][3][c]};
            f32x4 i4 = {Pim[p][0][c], Pim[p][1][c], Pim[p][2][c], Pim[p][3][c]};
            __builtin_nontemporal_store(r4, (f32x4*)(orow + j * 256 + lane * 4));
            __builtin_nontemporal_store(i4, (f32x4*)(orow + DIMQ + j * 256 + lane * 4));
        }
}

extern "C" void kernel_launch(void* const* d_in, const int* in_sizes, int n_in,
                              void* d_out, int out_size, void* d_ws, size_t ws_size,
                              hipStream_t stream) {
    const float* x      = (const float*)d_in[0];
    const float* alphas = (const float*)d_in[1];
    const float* betas  = (const float*)d_in[2];
    const float* thetas = (const float*)d_in[3];
    const float* phis   = (const float*)d_in[4];
    float* out = (float*)d_out;

    const int blocks = BATCH_ROWS / 4;  // 4 waves (rows) per 256-thread block

    if (ws_size >= NQ * 8 * sizeof(float)) {
        float* M = (float*)d_ws;
        qmat_precompute<<<1, 64, 0, stream>>>(alphas, betas, thetas, phis, M);
        qlayer_fused<true><<<blocks, 256, 0, stream>>>(x, M, alphas, betas, thetas, phis, out);
    } else {
        qlayer_fused<false><<<blocks, 256, 0, stream>>>(x, nullptr, alphas, betas, thetas, phis, out);
    }
}